// Round 12
// baseline (162.989 us; speedup 1.0000x reference)
//
#include <hip/hip_runtime.h>
#include <math.h>

#define L_SEQ 4096
#define C_DIM 256
#define H_HEADS 8
#define K_MAX 64
#define D_HEAD 32
#define HALF_W 32
#define N_OFF 65          // 2*HALF_W + 1
#define HK 512            // H_HEADS * K_MAX

__device__ __forceinline__ float sigmoidf_(float x) { return 1.0f / (1.0f + expf(-x)); }

// ================= K1: fused projection GEMM =================
// BM=128, BN=64, BK=16, TM=8, TN=8, 128 threads (2 waves), grid (12, 32) = 384.
// __launch_bounds__(128,2): VGPR cap 256, ~120 needed -> no spill (R8 retried right).
// Per-output sequential-k fmaf chain => kwbuf/vbuf bitwise identical.
__global__ void __launch_bounds__(128, 2)
proj_gemm(const float* __restrict__ A, const float* __restrict__ kw_w,
          const float* __restrict__ vw, const float* __restrict__ kb,
          const float* __restrict__ vb,
          float* __restrict__ kwbuf, float* __restrict__ vbuf) {
    __shared__ float As[16][132];   // [k][m]
    __shared__ float Bs[16][68];    // [k][n]

    const int tid = threadIdx.x;      // 0..127
    const int tx = tid & 7;           // 0..7  (8 cols each)
    const int ty = tid >> 3;          // 0..15 (8 rows each)
    const int l0 = blockIdx.y * 128;
    const int n0 = blockIdx.x * 64;

    const int arow = tid;             // one full row (16 k) per thread
    const int bk = tid >> 3;          // 0..15
    const int bn = (tid & 7) * 8;     // 0..56

    const float* Bsrc;
    int ldb, coff;
    if (n0 < 512) { Bsrc = kw_w; ldb = 512; coff = n0; }
    else          { Bsrc = vw;   ldb = 256; coff = n0 - 512; }

    float acc[8][8];
#pragma unroll
    for (int i = 0; i < 8; ++i)
#pragma unroll
        for (int jj = 0; jj < 8; ++jj) acc[i][jj] = 0.0f;

    const float* arow_p = A + (l0 + arow) * C_DIM;
    float4 a0 = *(const float4*)&arow_p[0];
    float4 a1 = *(const float4*)&arow_p[4];
    float4 a2 = *(const float4*)&arow_p[8];
    float4 a3 = *(const float4*)&arow_p[12];
    float4 b0 = *(const float4*)&Bsrc[bk * ldb + coff + bn];
    float4 b1 = *(const float4*)&Bsrc[bk * ldb + coff + bn + 4];

    for (int k0 = 0; k0 < C_DIM; k0 += 16) {
        __syncthreads();
        As[0][arow]  = a0.x; As[1][arow]  = a0.y; As[2][arow]  = a0.z; As[3][arow]  = a0.w;
        As[4][arow]  = a1.x; As[5][arow]  = a1.y; As[6][arow]  = a1.z; As[7][arow]  = a1.w;
        As[8][arow]  = a2.x; As[9][arow]  = a2.y; As[10][arow] = a2.z; As[11][arow] = a2.w;
        As[12][arow] = a3.x; As[13][arow] = a3.y; As[14][arow] = a3.z; As[15][arow] = a3.w;
        *(float4*)&Bs[bk][bn]     = b0;
        *(float4*)&Bs[bk][bn + 4] = b1;
        __syncthreads();
        if (k0 + 16 < C_DIM) {
            a0 = *(const float4*)&arow_p[k0 + 16 + 0];
            a1 = *(const float4*)&arow_p[k0 + 16 + 4];
            a2 = *(const float4*)&arow_p[k0 + 16 + 8];
            a3 = *(const float4*)&arow_p[k0 + 16 + 12];
            b0 = *(const float4*)&Bsrc[(k0 + 16 + bk) * ldb + coff + bn];
            b1 = *(const float4*)&Bsrc[(k0 + 16 + bk) * ldb + coff + bn + 4];
        }
#pragma unroll
        for (int kk = 0; kk < 16; ++kk) {
            const float4 alo = *(const float4*)&As[kk][ty * 8];
            const float4 ahi = *(const float4*)&As[kk][ty * 8 + 4];
            const float4 blo = *(const float4*)&Bs[kk][tx * 8];
            const float4 bhi = *(const float4*)&Bs[kk][tx * 8 + 4];
            const float ar[8] = {alo.x, alo.y, alo.z, alo.w, ahi.x, ahi.y, ahi.z, ahi.w};
            const float br[8] = {blo.x, blo.y, blo.z, blo.w, bhi.x, bhi.y, bhi.z, bhi.w};
#pragma unroll
            for (int i = 0; i < 8; ++i)
#pragma unroll
                for (int jj = 0; jj < 8; ++jj)
                    acc[i][jj] = fmaf(ar[i], br[jj], acc[i][jj]);
        }
    }

    const int g0 = n0 + tx * 8;
    float4 bz0, bz1;
    float* dst;
    int stride, col;
    if (g0 < 512) {
        bz0 = *(const float4*)&kb[g0]; bz1 = *(const float4*)&kb[g0 + 4];
        dst = kwbuf; stride = 512; col = g0;
    } else {
        bz0 = *(const float4*)&vb[g0 - 512]; bz1 = *(const float4*)&vb[g0 - 508];
        dst = vbuf; stride = 256; col = g0 - 512;
    }
#pragma unroll
    for (int i = 0; i < 8; ++i) {
        const int row = l0 + ty * 8 + i;
        float4 o0, o1;
        o0.x = acc[i][0] + bz0.x; o0.y = acc[i][1] + bz0.y;
        o0.z = acc[i][2] + bz0.z; o0.w = acc[i][3] + bz0.w;
        o1.x = acc[i][4] + bz1.x; o1.y = acc[i][5] + bz1.y;
        o1.z = acc[i][6] + bz1.z; o1.w = acc[i][7] + bz1.w;
        *(float4*)&dst[row * stride + col]     = o0;
        *(float4*)&dst[row * stride + col + 4] = o1;
    }
}

// ================= K2: fused norm + small-proj + conv (1 row, 256 thr) =================
// R10 footprint (16 KB LDS, 4096 blocks) + R11's proven-bitwise restructurings:
// concurrent kwraw-load/phase-B, butterfly rmsnorm tail, stage2 || stage1.5.
__global__ void __launch_bounds__(256, 2)
conv_fused(const float* __restrict__ x,
           const float* __restrict__ ww, const float* __restrict__ wb,
           const float* __restrict__ wg,
           const float* __restrict__ ow, const float* __restrict__ ob,
           const float* __restrict__ og,
           const float* __restrict__ kg,
           const float* __restrict__ kwraw, const float* __restrict__ v,
           float* __restrict__ out) {
    const int l = blockIdx.x;
    const int tid = threadIdx.x;

    __shared__ float red[256];
    __shared__ float rs_s;
    __shared__ float kwrow[HK];
    __shared__ float wsz[H_HEADS], ofs[H_HEADS];
    __shared__ float4 tap[H_HEADS][N_OFF];      // {attn, frac, as_float(offF), as_float(offC)}
    __shared__ float2 warr[H_HEADS][N_OFF + 1]; // {combined weight, as_float(rowoff)}
    __shared__ float inv_denom[H_HEADS];
    __shared__ int okflag;

    if (tid == 0) okflag = 1;

    // ---- Segment 1: waves 2-3 load kwraw + square-sums  ||  wave 0 = phase B ----
    float z0a = 0, z0b = 0, z1a = 0, z1b = 0;
    if (tid >= 128) {
        const int j0 = tid - 128;      // 0..127
        const int j1 = tid;            // 128..255
        const float* row = kwraw + l * HK;
        z0a = row[j0]; z0b = row[j0 + 256];
        z1a = row[j1]; z1b = row[j1 + 256];
        red[j0] = z0a * z0a + z0b * z0b;   // same slot content as R10's red[j]
        red[j1] = z1a * z1a + z1b * z1b;
    } else if (tid < 64) {
        // Phase B: small projections — bitwise == R10 wave-0 body
        const int lane = tid;
        const float* xr = x + l * C_DIM;
        float accw[H_HEADS], acco[H_HEADS];
#pragma unroll
        for (int h = 0; h < H_HEADS; ++h) { accw[h] = 0.0f; acco[h] = 0.0f; }
#pragma unroll
        for (int i = 0; i < C_DIM / 64; ++i) {
            const int c = lane + i * 64;
            const float xv = xr[c];
            const float* wwc = ww + c * H_HEADS;
            const float* owc = ow + c * H_HEADS;
#pragma unroll
            for (int h = 0; h < H_HEADS; ++h) {
                accw[h] = fmaf(xv, wwc[h], accw[h]);
                acco[h] = fmaf(xv, owc[h], acco[h]);
            }
        }
#pragma unroll
        for (int off = 32; off > 0; off >>= 1) {
#pragma unroll
            for (int h = 0; h < H_HEADS; ++h) {
                accw[h] += __shfl_xor(accw[h], off);
                acco[h] += __shfl_xor(acco[h], off);
            }
        }
        if (lane < H_HEADS) {
            float zw[H_HEADS], zo[H_HEADS];
            float ssw = 0.0f, sso = 0.0f;
#pragma unroll
            for (int h = 0; h < H_HEADS; ++h) {
                zw[h] = accw[h] + wb[h];
                zo[h] = acco[h] + ob[h];
                ssw += zw[h] * zw[h];
                sso += zo[h] * zo[h];
            }
            const float rw = rsqrtf(ssw / (float)H_HEADS + 1e-6f);
            const float ro = rsqrtf(sso / (float)H_HEADS + 1e-6f);
            const float nw = wg[lane] * zw[lane] * rw;
            const float no = og[lane] * zo[lane] * ro;
            wsz[lane] = 1.0f + sigmoidf_(nw) * 63.0f;
            ofs[lane] = tanhf(no) * 64.0f;
        }
    }
    __syncthreads();

    // ---- rmsnorm tree: s=128 (LDS), then wave-0 reg + butterfly (bitwise == tree) ----
    if (tid < 128) red[tid] += red[tid + 128];
    __syncthreads();
    if (tid < 64) {
        float s = red[tid] + red[tid + 64];
#pragma unroll
        for (int off = 32; off > 0; off >>= 1) s += __shfl_xor(s, off);
        if (tid == 0) rs_s = rsqrtf(s / (float)HK + 1e-6f);
    }
    __syncthreads();

    // ---- rmsnorm epilogue (loader threads hold the z values; same per-j exprs) ----
    if (tid >= 128) {
        const float rs = rs_s;
        const int j0 = tid - 128, j1 = tid;
        float n;
        n = kg[j0]       * z0a * rs; kwrow[j0]       = n * sigmoidf_(n);
        n = kg[j0 + 256] * z0b * rs; kwrow[j0 + 256] = n * sigmoidf_(n);
        n = kg[j1]       * z1a * rs; kwrow[j1]       = n * sigmoidf_(n);
        n = kg[j1 + 256] * z1b * rs; kwrow[j1 + 256] = n * sigmoidf_(n);
    }
    __syncthreads();

    // ---- Stage 1: attention taps (bitwise == R10) ----
    for (int t = tid; t < H_HEADS * N_OFF; t += 256) {
        const int h = t / N_OFF;
        const int n = t - h * N_OFF;
        const float ws  = wsz[h];
        const float off = ofs[h];
        const float local = (float)(n - HALF_W);
        const float neighbor = (float)l + off + local;
        const bool valid = (neighbor >= 0.0f) && (neighbor < (float)L_SEQ);
        const float nc = fminf(fmaxf(neighbor, 0.0f), (float)(L_SEQ - 1));

        const float rel = fabsf(local) / (ws * 0.5f + 1e-6f);
        const float mask = sigmoidf_(5.0f * (1.0f - rel)) * (valid ? 1.0f : 0.0f);

        const float kidx = fminf(rel, 1.0f) * (float)(K_MAX - 1);
        int ifl = (int)kidx;
        ifl = min(ifl, K_MAX - 2);
        const float wce = kidx - (float)ifl;
        const float kf = kwrow[h * K_MAX + ifl];
        const float kc = kwrow[h * K_MAX + ifl + 1];
        const float attnv = (kf * (1.0f - wce) + kc * wce) * mask;

        int p = (int)floorf(nc);
        p = min(max(p, 0), L_SEQ - 1);
        const int pc = min(p + 1, L_SEQ - 1);
        const float fr = nc - (float)p;

        float4 tv;
        tv.x = attnv;
        tv.y = fr;
        tv.z = __int_as_float(p * C_DIM + h * D_HEAD);
        tv.w = __int_as_float(pc * C_DIM + h * D_HEAD);
        tap[h][n] = tv;
    }
    __syncthreads();

    // ---- Stage 2 (tid<8, serial n order == R10)  ||  Stage 1.5 (rest) ----
    if (tid < 8) {
        float s = 0.0f;
        for (int n = 0; n < N_OFF; ++n) s += tap[tid][n].x;
        inv_denom[tid] = 1.0f / (s + 1e-6f);
    } else {
        for (int t = tid - 8; t < H_HEADS * (N_OFF + 1); t += 248) {
            const int h = t / (N_OFF + 1);
            const int m = t - h * (N_OFF + 1);
            float w, rowf;
            if (m == 0) {
                const float4 cur = tap[h][0];
                w = cur.x * (1.0f - cur.y);
                rowf = cur.z;
            } else {
                const float4 prev = tap[h][m - 1];
                const float wc = prev.x * prev.y;
                if (m < N_OFF) {
                    const float4 cur = tap[h][m];
                    w = cur.x * (1.0f - cur.y) + wc;
                    rowf = cur.z;
                    if (wc != 0.0f && __float_as_int(prev.w) != __float_as_int(cur.z))
                        okflag = 0;   // benign race: all writers store 0
                } else {
                    w = wc;
                    rowf = prev.w;
                }
            }
            warr[h][m] = make_float2(w, rowf);
        }
    }
    __syncthreads();

    // ---- Stage 3: gather & accumulate (bitwise == R10) ----
    const int h = tid >> 5;
    const int d = tid & 31;
    float acc = 0.0f;
    if (okflag) {
#pragma unroll 6
        for (int m = 0; m < N_OFF + 1; ++m) {
            const float2 t2 = warr[h][m];
            acc = fmaf(t2.x, v[__float_as_int(t2.y) + d], acc);
        }
    } else {
#pragma unroll 5
        for (int n = 0; n < N_OFF; ++n) {
            const float4 t4 = tap[h][n];
            const int bf = __float_as_int(t4.z);
            const int bc = __float_as_int(t4.w);
            const float vf = v[bf + d];
            const float vc = v[bc + d];
            acc = fmaf(t4.x, fmaf(t4.y, vc - vf, vf), acc);
        }
    }
    out[l * C_DIM + h * D_HEAD + d] = acc * inv_denom[h];
}

// ================= K3: out projection GEMM + silu (unchanged from round 10) =================
__global__ void __launch_bounds__(256, 4)
out_gemm(const float* __restrict__ A, const float* __restrict__ W,
         float* __restrict__ out) {
    __shared__ float As[16][68];
    __shared__ float Bs[16][68];

    const int tid = threadIdx.x;
    const int tx = tid & 15;
    const int ty = tid >> 4;
    const int l0 = blockIdx.y * 64;
    const int n0 = blockIdx.x * 64;

    const int am = tid >> 2;
    const int ak = (tid & 3) * 4;
    const int bk = tid >> 4;
    const int bn = (tid & 15) * 4;

    float acc[4][4];
#pragma unroll
    for (int i = 0; i < 4; ++i)
#pragma unroll
        for (int jj = 0; jj < 4; ++jj) acc[i][jj] = 0.0f;

    float4 av = *(const float4*)&A[(l0 + am) * C_DIM + ak];
    float4 bv = *(const float4*)&W[bk * C_DIM + n0 + bn];

    for (int k0 = 0; k0 < C_DIM; k0 += 16) {
        __syncthreads();
        As[ak + 0][am] = av.x;
        As[ak + 1][am] = av.y;
        As[ak + 2][am] = av.z;
        As[ak + 3][am] = av.w;
        *(float4*)&Bs[bk][bn] = bv;
        __syncthreads();
        if (k0 + 16 < C_DIM) {
            av = *(const float4*)&A[(l0 + am) * C_DIM + (k0 + 16) + ak];
            bv = *(const float4*)&W[(k0 + 16 + bk) * C_DIM + n0 + bn];
        }
#pragma unroll
        for (int kk = 0; kk < 16; ++kk) {
            const float4 a4 = *(const float4*)&As[kk][ty * 4];
            const float4 b4 = *(const float4*)&Bs[kk][tx * 4];
            const float ar[4] = {a4.x, a4.y, a4.z, a4.w};
            const float br[4] = {b4.x, b4.y, b4.z, b4.w};
#pragma unroll
            for (int i = 0; i < 4; ++i)
#pragma unroll
                for (int jj = 0; jj < 4; ++jj)
                    acc[i][jj] = fmaf(ar[i], br[jj], acc[i][jj]);
        }
    }

    const int g0 = n0 + tx * 4;
#pragma unroll
    for (int i = 0; i < 4; ++i) {
        const int row = l0 + ty * 4 + i;
        float4 o;
        o.x = acc[i][0] * sigmoidf_(acc[i][0]);
        o.y = acc[i][1] * sigmoidf_(acc[i][1]);
        o.z = acc[i][2] * sigmoidf_(acc[i][2]);
        o.w = acc[i][3] * sigmoidf_(acc[i][3]);
        *(float4*)&out[row * C_DIM + g0] = o;
    }
}

extern "C" void kernel_launch(void* const* d_in, const int* in_sizes, int n_in,
                              void* d_out, int out_size, void* d_ws, size_t ws_size,
                              hipStream_t stream) {
    const float* x    = (const float*)d_in[0];
    const float* ww   = (const float*)d_in[1];
    const float* wb   = (const float*)d_in[2];
    const float* wg   = (const float*)d_in[3];
    const float* ow   = (const float*)d_in[4];
    const float* ob   = (const float*)d_in[5];
    const float* og   = (const float*)d_in[6];
    const float* kw_w = (const float*)d_in[7];
    const float* kb   = (const float*)d_in[8];
    const float* kg   = (const float*)d_in[9];
    const float* vw   = (const float*)d_in[10];
    const float* vb   = (const float*)d_in[11];
    const float* outw = (const float*)d_in[12];
    float* y = (float*)d_out;

    float* ws_f    = (float*)d_ws;
    float* kwbuf   = ws_f;                       // 4096*512 (raw z+bias)
    float* vbuf    = kwbuf + L_SEQ * HK;         // 4096*256
    float* convbuf = vbuf + L_SEQ * C_DIM;       // 4096*256

    proj_gemm<<<dim3(12, L_SEQ / 128), 128, 0, stream>>>(x, kw_w, vw, kb, vb, kwbuf, vbuf);
    conv_fused<<<L_SEQ, 256, 0, stream>>>(x, ww, wb, wg, ow, ob, og, kg, kwbuf, vbuf, convbuf);
    out_gemm<<<dim3(C_DIM / 64, L_SEQ / 64), 256, 0, stream>>>(convbuf, outw, y);
}